// Round 4
// baseline (189.622 us; speedup 1.0000x reference)
//
#include <hip/hip_runtime.h>
#include <math.h>

#define HW    409600      // 640*640
#define HW4   102400      // float4-quads per (batch,dim)
#define BATCH 8
#define NLAB  33
#define GXB   400         // blocks per batch; 1 quad per thread
#define NREP  8           // LDS bin replicas (per 8-lane cluster)
#define RS    201         // replica stride, 201%32=9 spreads banks
// ws float layout per batch (stride WSB): sums[132] cnt_k[33]@132 cnt_i[33]@165 valsum@198
#define WSB   208
#define LAB_OFF 8192      // byte offset of packed label array in ws
#define LAB_BYTES (4u * HW4 * BATCH)

__global__ void init_ws(float* ws, float* out) {
    int i = blockIdx.x * 256 + threadIdx.x;
    if (i < WSB * BATCH) ws[i] = 0.f;
    if (i == 0) out[0] = 0.f;    // final_kernel accumulates into out
}

__device__ __forceinline__ float getc(const float4& v, int e) {
    return (e == 0) ? v.x : (e == 1) ? v.y : (e == 2) ? v.z : v.w;
}

__device__ __forceinline__ float wave_sum(float v) {
    #pragma unroll
    for (int o = 32; o > 0; o >>= 1) v += __shfl_xor(v, o);
    return v;
}

__device__ __forceinline__ void acc1(int l, bool k,
                                     float x0, float x1, float x2, float x3,
                                     float* mb) {
    if (l) {
        float* bb = mb + l * 6;
        atomicAdd(bb + 5, 1.f);          // cnt_i
        if (k) {
            atomicAdd(bb + 0, x0);
            atomicAdd(bb + 1, x1);
            atomicAdd(bb + 2, x2);
            atomicAdd(bb + 3, x3);
            atomicAdd(bb + 4, 1.f);      // cnt_k
        }
    }
}

__global__ __launch_bounds__(256, 8) void pass1(const float* __restrict__ emb,
                                                const int*   __restrict__ inst,
                                                const float* __restrict__ kern,
                                                const float* __restrict__ tmask,
                                                float*       __restrict__ ws,
                                                unsigned*    __restrict__ labs) {
    __shared__ float bins[NREP][RS];
    const int t = threadIdx.x, bx = blockIdx.x, b = blockIdx.y;
    float* mb = bins[(t >> 3) & (NREP - 1)];

    const size_t  base  = (size_t)b * HW;
    const float4* emb4  = (const float4*)(emb + base * 4);
    const int4*   inst4 = (const int4*)(inst + base);
    const float4* kern4 = (const float4*)(kern + base);
    const float4* tm4   = (const float4*)(tmask + base);
    const int g = bx * 256 + t;

    // issue all 7 independent loads first; latency overlaps LDS zero + barrier
    int4   iv = inst4[g];
    float4 tv = tm4[g];
    float4 kv = kern4[g];
    float4 x0 = emb4[g];
    float4 x1 = emb4[g + HW4];
    float4 x2 = emb4[g + 2 * HW4];
    float4 x3 = emb4[g + 3 * HW4];

    for (int i = t; i < NREP * RS; i += 256) (&bins[0][0])[i] = 0.f;
    __syncthreads();

    int l0 = (tv.x > 0.5f) ? iv.x : 0;
    int l1 = (tv.y > 0.5f) ? iv.y : 0;
    int l2 = (tv.z > 0.5f) ? iv.z : 0;
    int l3 = (tv.w > 0.5f) ? iv.w : 0;

    if (labs)
        labs[(size_t)b * HW4 + g] = (unsigned)l0 | ((unsigned)l1 << 8) |
                                    ((unsigned)l2 << 16) | ((unsigned)l3 << 24);

    acc1(l0, kv.x > 0.5f, x0.x, x1.x, x2.x, x3.x, mb);
    acc1(l1, kv.y > 0.5f, x0.y, x1.y, x2.y, x3.y, mb);
    acc1(l2, kv.z > 0.5f, x0.z, x1.z, x2.z, x3.z, mb);
    acc1(l3, kv.w > 0.5f, x0.w, x1.w, x2.w, x3.w, mb);
    __syncthreads();

    float* w = ws + b * WSB;
    for (int i = t; i < NLAB * 6; i += 256) {
        float v = 0.f;
        #pragma unroll
        for (int r = 0; r < NREP; ++r) v += bins[r][i];
        if (v != 0.f) {
            int lab = i / 6, f = i % 6;
            int dst = (f < 4) ? lab * 4 + f : ((f == 4) ? 132 + lab : 165 + lab);
            atomicAdd(w + dst, v);
        }
    }
}

template<bool USE_LABS>
__global__ __launch_bounds__(256, 8) void pass2(const float* __restrict__ emb,
                                                const int*   __restrict__ inst,
                                                const float* __restrict__ tmask,
                                                float*       __restrict__ ws,
                                                const unsigned* __restrict__ labs) {
    __shared__ float4 means4[NLAB];
    __shared__ float  invci[NLAB];
    __shared__ float  red[4];
    const int t = threadIdx.x, bx = blockIdx.x, b = blockIdx.y;
    float* w = ws + b * WSB;

    const size_t  base = (size_t)b * HW;
    const float4* emb4 = (const float4*)(emb + base * 4);
    const int g = bx * 256 + t;

    // issue data loads first
    unsigned pk;
    if (USE_LABS) {
        pk = labs[(size_t)b * HW4 + g];
    } else {
        const int4*   inst4 = (const int4*)(inst + base);
        const float4* tm4   = (const float4*)(tmask + base);
        int4 iv = inst4[g];
        float4 tv = tm4[g];
        pk = (unsigned)((tv.x > 0.5f) ? iv.x : 0)        |
             ((unsigned)((tv.y > 0.5f) ? iv.y : 0) << 8) |
             ((unsigned)((tv.z > 0.5f) ? iv.z : 0) << 16)|
             ((unsigned)((tv.w > 0.5f) ? iv.w : 0) << 24);
    }
    float4 x0 = emb4[g];
    float4 x1 = emb4[g + HW4];
    float4 x2 = emb4[g + 2 * HW4];
    float4 x3 = emb4[g + 3 * HW4];

    if (t < NLAB) {
        float inv = 1.f / fmaxf(w[132 + t], 1.f);
        float z = (t == 0) ? 0.f : 1.f;
        means4[t] = make_float4(z * w[t * 4 + 0] * inv, z * w[t * 4 + 1] * inv,
                                z * w[t * 4 + 2] * inv, z * w[t * 4 + 3] * inv);
        invci[t] = 1.f / fmaxf(w[165 + t], 1.f);
    }
    __syncthreads();

    float acc = 0.f;
    #pragma unroll
    for (int e = 0; e < 4; ++e) {
        int l = (pk >> (8 * e)) & 255;
        if (l) {
            float4 m = means4[l];
            float d0 = getc(x0, e) - m.x, d1 = getc(x1, e) - m.y;
            float d2 = getc(x2, e) - m.z, d3 = getc(x3, e) - m.w;
            float dist = sqrtf(d0 * d0 + d1 * d1 + d2 * d2 + d3 * d3);
            float u = fmaxf(dist - 0.5f, 0.f);
            acc += __logf(u * u + 1.f) * invci[l];
        }
    }

    acc = wave_sum(acc);
    if ((t & 63) == 0) red[t >> 6] = acc;
    __syncthreads();
    if (t == 0) atomicAdd(w + 198, red[0] + red[1] + red[2] + red[3]);
}

__global__ __launch_bounds__(256) void final_kernel(const float* __restrict__ ws,
                                                    float* __restrict__ out) {
    __shared__ float4 means4[NLAB];
    __shared__ float  red[4];
    const int t = threadIdx.x, b = blockIdx.x;
    const float* w = ws + b * WSB;

    if (t < NLAB) {
        float inv = 1.f / fmaxf(w[132 + t], 1.f);
        float z = (t == 0) ? 0.f : 1.f;
        means4[t] = make_float4(z * w[t * 4 + 0] * inv, z * w[t * 4 + 1] * inv,
                                z * w[t * 4 + 2] * inv, z * w[t * 4 + 3] * inv);
    }
    __syncthreads();

    float part = 0.f;
    if (t == 0) part = w[198] * (1.f / 32.f);                 // l_agg
    float disp = 0.f;
    for (int p = t; p < 1024; p += 256) {
        int i = p >> 5, j = p & 31;
        if (i != j) {
            float4 mi = means4[i + 1], mj = means4[j + 1];
            float d0 = mi.x - mj.x, d1 = mi.y - mj.y;
            float d2 = mi.z - mj.z, d3 = mi.w - mj.w;
            float pd = sqrtf(d0 * d0 + d1 * d1 + d2 * d2 + d3 * d3);
            float u = fmaxf(3.0f - pd, 0.f);
            disp += __logf(u * u + 1.f);
        }
    }
    disp *= 1.f / 992.f;                                      // 32*31
    float regp = 0.f;
    if (t >= 1 && t < NLAB) {
        float4 m = means4[t];
        float n2 = m.x * m.x + m.y * m.y + m.z * m.z + m.w * m.w;
        regp = __logf(sqrtf(n2) + 1.f) * (0.001f / 33.f);
    }

    float v = wave_sum(part + disp + regp);
    if ((t & 63) == 0) red[t >> 6] = v;
    __syncthreads();
    if (t == 0)
        atomicAdd(out, (red[0] + red[1] + red[2] + red[3]) * (1.f / BATCH));
}

extern "C" void kernel_launch(void* const* d_in, const int* in_sizes, int n_in,
                              void* d_out, int out_size, void* d_ws, size_t ws_size,
                              hipStream_t stream) {
    const float* emb   = (const float*)d_in[0];
    const int*   inst  = (const int*)  d_in[1];
    const float* kern  = (const float*)d_in[2];
    const float* tmask = (const float*)d_in[3];
    float* ws  = (float*)d_ws;
    float* out = (float*)d_out;

    const bool use_labs = ws_size >= (size_t)LAB_OFF + LAB_BYTES;
    unsigned* labs = use_labs ? (unsigned*)((char*)d_ws + LAB_OFF) : nullptr;

    init_ws<<<dim3((WSB * BATCH + 255) / 256), 256, 0, stream>>>(ws, out);
    dim3 grid(GXB, BATCH);
    pass1<<<grid, 256, 0, stream>>>(emb, inst, kern, tmask, ws, labs);
    if (use_labs) pass2<true ><<<grid, 256, 0, stream>>>(emb, inst, tmask, ws, labs);
    else          pass2<false><<<grid, 256, 0, stream>>>(emb, inst, tmask, ws, nullptr);
    final_kernel<<<BATCH, 256, 0, stream>>>(ws, out);
}

// Round 5
// 156.689 us; speedup vs baseline: 1.2102x; 1.2102x over previous
//
#include <hip/hip_runtime.h>
#include <math.h>

#define HW    409600      // 640*640
#define HW4   102400      // float4-quads per (batch,dim)
#define BATCH 8
#define NLAB  33
#define GXB1  100         // pass1/pass2 blocks per batch; 4 quads/thread
#define NREP  8           // LDS bin replicas (per 8-lane cluster)
#define RS    201         // replica stride
// ws float-offset layout:
#define MEANS_OFF 0                        // [8][168]: mean[132], invci[33], pad
#define AWS_OFF   1344                     // [8][208] atomic-fallback bins
#define P2_OFF    3008                     // [8][128] pass2 val partials
#define P1_OFF    4096                     // [8][100][200] pass1 partials (split mode)
#define LABS_OFF_F 164096                  // u32 [8][HW4] packed labels
#define NEED_SPLIT ((size_t)(P1_OFF + BATCH*GXB1*200) * 4)
#define NEED_LABS  ((size_t)LABS_OFF_F * 4 + (size_t)BATCH * HW4 * 4)

#if defined(__has_builtin) && __has_builtin(__builtin_amdgcn_sched_barrier)
#define SCHED_PIN() __builtin_amdgcn_sched_barrier(0)
#else
#define SCHED_PIN()
#endif

__global__ void init_ws(float* ws, float* out) {
    int t = threadIdx.x;
    for (int i = t; i < AWS_OFF + BATCH * 208 - 0; i += 256)
        if (i >= AWS_OFF) ws[i] = 0.f;     // zero atomic-fallback region only
    if (t == 0) out[0] = 0.f;
}

__device__ __forceinline__ float getc(const float4& v, int e) {
    return (e == 0) ? v.x : (e == 1) ? v.y : (e == 2) ? v.z : v.w;
}
__device__ __forceinline__ float wave_sum(float v) {
    #pragma unroll
    for (int o = 32; o > 0; o >>= 1) v += __shfl_xor(v, o);
    return v;
}

// ---------------- pass1 ----------------
struct Quad { int4 iv; float4 tv, kv, x0, x1, x2, x3; };

__device__ __forceinline__ void loadQ(Quad& q, const int4* inst4, const float4* tm4,
                                      const float4* kern4, const float4* emb4, int g) {
    q.iv = inst4[g];
    q.tv = tm4[g];
    q.kv = kern4[g];
    q.x0 = emb4[g];
    q.x1 = emb4[g + HW4];
    q.x2 = emb4[g + 2 * HW4];
    q.x3 = emb4[g + 3 * HW4];
}

__device__ __forceinline__ void acc1(int l, bool k,
                                     float x0, float x1, float x2, float x3,
                                     float* mb) {
    if (l) {
        float* bb = mb + l * 6;
        atomicAdd(bb + 5, 1.f);          // cnt_i
        if (k) {
            atomicAdd(bb + 0, x0);
            atomicAdd(bb + 1, x1);
            atomicAdd(bb + 2, x2);
            atomicAdd(bb + 3, x3);
            atomicAdd(bb + 4, 1.f);      // cnt_k
        }
    }
}

__device__ __forceinline__ void procQ(const Quad& q, float* mb,
                                      unsigned* labs, size_t labidx) {
    int l0 = (q.tv.x > 0.5f) ? q.iv.x : 0;
    int l1 = (q.tv.y > 0.5f) ? q.iv.y : 0;
    int l2 = (q.tv.z > 0.5f) ? q.iv.z : 0;
    int l3 = (q.tv.w > 0.5f) ? q.iv.w : 0;
    if (labs)
        labs[labidx] = (unsigned)l0 | ((unsigned)l1 << 8) |
                       ((unsigned)l2 << 16) | ((unsigned)l3 << 24);
    acc1(l0, q.kv.x > 0.5f, q.x0.x, q.x1.x, q.x2.x, q.x3.x, mb);
    acc1(l1, q.kv.y > 0.5f, q.x0.y, q.x1.y, q.x2.y, q.x3.y, mb);
    acc1(l2, q.kv.z > 0.5f, q.x0.z, q.x1.z, q.x2.z, q.x3.z, mb);
    acc1(l3, q.kv.w > 0.5f, q.x0.w, q.x1.w, q.x2.w, q.x3.w, mb);
}

template<bool SPLIT>
__global__ __launch_bounds__(256, 4) void pass1(const float* __restrict__ emb,
                                                const int*   __restrict__ inst,
                                                const float* __restrict__ kern,
                                                const float* __restrict__ tmask,
                                                float*       __restrict__ ws,
                                                unsigned*    __restrict__ labs) {
    __shared__ float bins[NREP][RS];
    const int t = threadIdx.x, bx = blockIdx.x, b = blockIdx.y;
    float* mb = bins[(t >> 3) & (NREP - 1)];

    const size_t  base  = (size_t)b * HW;
    const float4* emb4  = (const float4*)(emb + base * 4);
    const int4*   inst4 = (const int4*)(inst + base);
    const float4* kern4 = (const float4*)(kern + base);
    const float4* tm4   = (const float4*)(tmask + base);
    const int q0 = bx * 1024 + t;                 // chunk c: q0 + c*256
    const size_t lb = (size_t)b * HW4;

    Quad c0, c1;
    loadQ(c0, inst4, tm4, kern4, emb4, q0);
    loadQ(c1, inst4, tm4, kern4, emb4, q0 + 256);
    SCHED_PIN();

    for (int i = t; i < NREP * RS; i += 256) (&bins[0][0])[i] = 0.f;
    __syncthreads();

    procQ(c0, mb, labs, lb + q0);
    loadQ(c0, inst4, tm4, kern4, emb4, q0 + 512);
    SCHED_PIN();
    procQ(c1, mb, labs, lb + q0 + 256);
    loadQ(c1, inst4, tm4, kern4, emb4, q0 + 768);
    SCHED_PIN();
    procQ(c0, mb, labs, lb + q0 + 512);
    procQ(c1, mb, labs, lb + q0 + 768);
    __syncthreads();

    if (t < NLAB * 6) {
        float v = 0.f;
        #pragma unroll
        for (int r = 0; r < NREP; ++r) v += bins[r][t];
        if (SPLIT) {
            ws[P1_OFF + ((size_t)b * GXB1 + bx) * 200 + t] = v;   // plain store
        } else {
            if (v != 0.f) atomicAdd(ws + AWS_OFF + b * 208 + t, v);
        }
    }
}

// ---------------- reduce: partials -> means/invci ----------------
template<bool SPLIT>
__global__ __launch_bounds__(256) void reduce_means(float* __restrict__ ws) {
    __shared__ float raw[200];
    const int t = threadIdx.x, b = blockIdx.x;
    if (t < NLAB * 6) {
        float s = 0.f;
        if (SPLIT) {
            const float* p = ws + P1_OFF + (size_t)b * GXB1 * 200;
            for (int bx = 0; bx < GXB1; ++bx) s += p[bx * 200 + t];
        } else {
            s = ws[AWS_OFF + b * 208 + t];
        }
        raw[t] = s;
    }
    __syncthreads();
    float* mm = ws + MEANS_OFF + b * 168;
    if (t < NLAB) {
        float cntk = raw[t * 6 + 4], cnti = raw[t * 6 + 5];
        float inv = 1.f / fmaxf(cntk, 1.f);
        float z = (t == 0) ? 0.f : 1.f;
        mm[t * 4 + 0] = z * raw[t * 6 + 0] * inv;
        mm[t * 4 + 1] = z * raw[t * 6 + 1] * inv;
        mm[t * 4 + 2] = z * raw[t * 6 + 2] * inv;
        mm[t * 4 + 3] = z * raw[t * 6 + 3] * inv;
        mm[132 + t]   = 1.f / fmaxf(cnti, 1.f);
    }
}

// ---------------- pass2 ----------------
struct Quad2 { unsigned pk; int4 iv; float4 tv, x0, x1, x2, x3; };

template<bool USE_LABS>
__device__ __forceinline__ void loadQ2(Quad2& q, const unsigned* labs, size_t lb,
                                       const int4* inst4, const float4* tm4,
                                       const float4* emb4, int g) {
    if (USE_LABS) {
        q.pk = labs[lb + g];
    } else {
        q.iv = inst4[g];
        q.tv = tm4[g];
    }
    q.x0 = emb4[g];
    q.x1 = emb4[g + HW4];
    q.x2 = emb4[g + 2 * HW4];
    q.x3 = emb4[g + 3 * HW4];
}

template<bool USE_LABS>
__device__ __forceinline__ float procQ2(const Quad2& q, const float4* means4,
                                        const float* invci) {
    unsigned pk;
    if (USE_LABS) {
        pk = q.pk;
    } else {
        pk = (unsigned)((q.tv.x > 0.5f) ? q.iv.x : 0)        |
             ((unsigned)((q.tv.y > 0.5f) ? q.iv.y : 0) << 8) |
             ((unsigned)((q.tv.z > 0.5f) ? q.iv.z : 0) << 16)|
             ((unsigned)((q.tv.w > 0.5f) ? q.iv.w : 0) << 24);
    }
    float acc = 0.f;
    #pragma unroll
    for (int e = 0; e < 4; ++e) {
        int l = (pk >> (8 * e)) & 255;
        if (l) {
            float4 m = means4[l];
            float d0 = getc(q.x0, e) - m.x, d1 = getc(q.x1, e) - m.y;
            float d2 = getc(q.x2, e) - m.z, d3 = getc(q.x3, e) - m.w;
            float dist = sqrtf(d0 * d0 + d1 * d1 + d2 * d2 + d3 * d3);
            float u = fmaxf(dist - 0.5f, 0.f);
            acc += __logf(u * u + 1.f) * invci[l];
        }
    }
    return acc;
}

template<bool USE_LABS>
__global__ __launch_bounds__(256, 4) void pass2(const float* __restrict__ emb,
                                                const int*   __restrict__ inst,
                                                const float* __restrict__ tmask,
                                                float*       __restrict__ ws,
                                                const unsigned* __restrict__ labs) {
    __shared__ float4 means4[NLAB];
    __shared__ float  invci[NLAB];
    __shared__ float  red[4];
    const int t = threadIdx.x, bx = blockIdx.x, b = blockIdx.y;

    const size_t  base  = (size_t)b * HW;
    const float4* emb4  = (const float4*)(emb + base * 4);
    const int4*   inst4 = (const int4*)(inst + base);
    const float4* tm4   = (const float4*)(tmask + base);
    const int q0 = bx * 1024 + t;
    const size_t lb = (size_t)b * HW4;

    Quad2 c0, c1;
    loadQ2<USE_LABS>(c0, labs, lb, inst4, tm4, emb4, q0);
    loadQ2<USE_LABS>(c1, labs, lb, inst4, tm4, emb4, q0 + 256);
    SCHED_PIN();

    const float* mm = ws + MEANS_OFF + b * 168;
    if (t < NLAB) {
        means4[t] = ((const float4*)mm)[t];
        invci[t]  = mm[132 + t];
    }
    __syncthreads();

    float acc = procQ2<USE_LABS>(c0, means4, invci);
    loadQ2<USE_LABS>(c0, labs, lb, inst4, tm4, emb4, q0 + 512);
    SCHED_PIN();
    acc += procQ2<USE_LABS>(c1, means4, invci);
    loadQ2<USE_LABS>(c1, labs, lb, inst4, tm4, emb4, q0 + 768);
    SCHED_PIN();
    acc += procQ2<USE_LABS>(c0, means4, invci);
    acc += procQ2<USE_LABS>(c1, means4, invci);

    acc = wave_sum(acc);
    if ((t & 63) == 0) red[t >> 6] = acc;
    __syncthreads();
    if (t == 0)
        ws[P2_OFF + b * 128 + bx] = red[0] + red[1] + red[2] + red[3];  // plain store
}

// ---------------- final ----------------
__global__ __launch_bounds__(256) void final_kernel(const float* __restrict__ ws,
                                                    float* __restrict__ out) {
    __shared__ float4 means4[NLAB];
    __shared__ float  red[4];
    const int t = threadIdx.x, b = blockIdx.x;
    const float* mm = ws + MEANS_OFF + b * 168;
    if (t < NLAB) means4[t] = ((const float4*)mm)[t];
    __syncthreads();

    float part = (t < GXB1) ? ws[P2_OFF + b * 128 + t] * (1.f / 32.f) : 0.f;  // l_agg
    float disp = 0.f;
    for (int p = t; p < 1024; p += 256) {
        int i = p >> 5, j = p & 31;
        if (i != j) {
            float4 mi = means4[i + 1], mj = means4[j + 1];
            float d0 = mi.x - mj.x, d1 = mi.y - mj.y;
            float d2 = mi.z - mj.z, d3 = mi.w - mj.w;
            float pd = sqrtf(d0 * d0 + d1 * d1 + d2 * d2 + d3 * d3);
            float u = fmaxf(3.0f - pd, 0.f);
            disp += __logf(u * u + 1.f);
        }
    }
    disp *= 1.f / 992.f;                                      // 32*31
    float regp = 0.f;
    if (t >= 1 && t < NLAB) {
        float4 m = means4[t];
        float n2 = m.x * m.x + m.y * m.y + m.z * m.z + m.w * m.w;
        regp = __logf(sqrtf(n2) + 1.f) * (0.001f / 33.f);
    }

    float v = wave_sum(part + disp + regp);
    if ((t & 63) == 0) red[t >> 6] = v;
    __syncthreads();
    if (t == 0)
        atomicAdd(out, (red[0] + red[1] + red[2] + red[3]) * (1.f / BATCH));
}

extern "C" void kernel_launch(void* const* d_in, const int* in_sizes, int n_in,
                              void* d_out, int out_size, void* d_ws, size_t ws_size,
                              hipStream_t stream) {
    const float* emb   = (const float*)d_in[0];
    const int*   inst  = (const int*)  d_in[1];
    const float* kern  = (const float*)d_in[2];
    const float* tmask = (const float*)d_in[3];
    float* ws  = (float*)d_ws;
    float* out = (float*)d_out;

    const bool split    = ws_size >= NEED_SPLIT;
    const bool use_labs = ws_size >= NEED_LABS;
    unsigned* labs = use_labs ? (unsigned*)(ws + LABS_OFF_F) : nullptr;

    init_ws<<<1, 256, 0, stream>>>(ws, out);
    dim3 grid(GXB1, BATCH);
    if (split) pass1<true ><<<grid, 256, 0, stream>>>(emb, inst, kern, tmask, ws, labs);
    else       pass1<false><<<grid, 256, 0, stream>>>(emb, inst, kern, tmask, ws, labs);
    if (split) reduce_means<true ><<<BATCH, 256, 0, stream>>>(ws);
    else       reduce_means<false><<<BATCH, 256, 0, stream>>>(ws);
    if (use_labs) pass2<true ><<<grid, 256, 0, stream>>>(emb, inst, tmask, ws, labs);
    else          pass2<false><<<grid, 256, 0, stream>>>(emb, inst, tmask, ws, nullptr);
    final_kernel<<<BATCH, 256, 0, stream>>>(ws, out);
}